// Round 11
// baseline (50.258 us; speedup 1.0000x reference)
//
#include <hip/hip_runtime.h>
#include <math.h>

#define NTOK 2048
#define CC   128
#define CPP  16
#define HH   8
#define DHH  16
#define NQW  32
#define NKW  128
#define PADW 48
#define NBW  64

__device__ __forceinline__ float sigm(float x) { return 1.0f / (1.0f + expf(-x)); }

// ---------------------------------------------------------------------------
// K1: blocks [0,256): LN + adaLN GEMM + 4 projections for 8 rows, 512 threads.
//     blocks [256,768): bias (4 tokens each).   (round-10 version, unchanged)
// ---------------------------------------------------------------------------
__global__ __launch_bounds__(512) void k1_fused(
    const float* __restrict__ x1, const float* __restrict__ x2,
    const float* __restrict__ gamma_s,
    const float* __restrict__ Wg_ada, const float* __restrict__ bg_ada,
    const float* __restrict__ W_skip,
    const float* __restrict__ Wq, const float* __restrict__ Wk,
    const float* __restrict__ Wv, const float* __restrict__ Wg,
    const float* __restrict__ bg,
    const float* __restrict__ pair,
    const float* __restrict__ gamma_p, const float* __restrict__ beta_p,
    const float* __restrict__ W_pair,
    float* __restrict__ qb, float* __restrict__ kb,
    float* __restrict__ vb, float* __restrict__ gb,
    float* __restrict__ bias)
{
  const int b   = blockIdx.x;
  const int tid = threadIdx.x;

  if (b < 256) {
    __shared__ float sln[8][132];
    __shared__ float aln[8][132];
    __shared__ float as_[8][132];
    const int r0 = b * 8;

    {
      const int r = tid >> 6, t = tid & 63, c0 = t * 2;
      const int row = r0 + r;
      float2 v1 = *(const float2*)(x1 + (size_t)row * CC + c0);
      float2 v2 = *(const float2*)(x2 + (size_t)row * CC + c0);
      float s1 = v1.x + v1.y, p1 = v1.x * v1.x + v1.y * v1.y;
      float s2 = v2.x + v2.y, p2 = v2.x * v2.x + v2.y * v2.y;
#pragma unroll
      for (int m = 1; m < 64; m <<= 1) {
        s1 += __shfl_xor(s1, m); p1 += __shfl_xor(p1, m);
        s2 += __shfl_xor(s2, m); p2 += __shfl_xor(p2, m);
      }
      const float rc = 1.0f / 128.0f;
      float mu1 = s1 * rc, mu2 = s2 * rc;
      float rs1 = rsqrtf(p1 * rc - mu1 * mu1 + 1e-5f);
      float rs2 = rsqrtf(p2 * rc - mu2 * mu2 + 1e-5f);
      float2 gs = *(const float2*)(gamma_s + c0);
      aln[r][c0]     = (v1.x - mu1) * rs1;
      aln[r][c0 + 1] = (v1.y - mu1) * rs1;
      sln[r][c0]     = (v2.x - mu2) * rs2 * gs.x;
      sln[r][c0 + 1] = (v2.y - mu2) * rs2 * gs.y;
    }
    __syncthreads();

    {
      const int rh = tid >> 7, cg = tid & 127;
      const int ra = rh * 2, rb = rh * 2 + 1;
      float g0 = 0.f, g1 = 0.f, s0 = 0.f, s1 = 0.f;
#pragma unroll 4
      for (int k4 = 0; k4 < 32; ++k4) {
        float4 a0 = *(const float4*)(&sln[ra][k4 * 4]);
        float4 a1 = *(const float4*)(&sln[rb][k4 * 4]);
#define S1STEP(AX, J) { \
        float wg = Wg_ada[(k4 * 4 + J) * CC + cg]; \
        float wk = W_skip[(k4 * 4 + J) * CC + cg]; \
        g0 = fmaf(a0.AX, wg, g0); g1 = fmaf(a1.AX, wg, g1); \
        s0 = fmaf(a0.AX, wk, s0); s1 = fmaf(a1.AX, wk, s1); }
        S1STEP(x, 0) S1STEP(y, 1) S1STEP(z, 2) S1STEP(w, 3)
#undef S1STEP
      }
      float bga = bg_ada[cg];
      as_[ra][cg] = sigm(g0 + bga) * aln[ra][cg] + s0;
      as_[rb][cg] = sigm(g1 + bga) * aln[rb][cg] + s1;
    }
    __syncthreads();

    {
      const int wv  = tid >> 6;
      const int m   = wv & 3;
      const int rh2 = wv >> 2;
      const int l   = tid & 63;
      const int c0  = l * 2;
      const int rb0 = rh2 * 4;
      const float* Wm = (m == 0) ? Wq : (m == 1) ? Wk : (m == 2) ? Wv : Wg;
      float2 c0_ = {0.f, 0.f}, c1_ = {0.f, 0.f}, c2_ = {0.f, 0.f}, c3_ = {0.f, 0.f};
#pragma unroll 4
      for (int k4 = 0; k4 < 32; ++k4) {
        float4 ra0 = *(const float4*)(&as_[rb0 + 0][k4 * 4]);
        float4 ra1 = *(const float4*)(&as_[rb0 + 1][k4 * 4]);
        float4 ra2 = *(const float4*)(&as_[rb0 + 2][k4 * 4]);
        float4 ra3 = *(const float4*)(&as_[rb0 + 3][k4 * 4]);
#define PJSTEP(AX, J) { \
        float2 wv2 = *(const float2*)(Wm + (k4 * 4 + J) * CC + c0); \
        c0_.x = fmaf(ra0.AX, wv2.x, c0_.x); c0_.y = fmaf(ra0.AX, wv2.y, c0_.y); \
        c1_.x = fmaf(ra1.AX, wv2.x, c1_.x); c1_.y = fmaf(ra1.AX, wv2.y, c1_.y); \
        c2_.x = fmaf(ra2.AX, wv2.x, c2_.x); c2_.y = fmaf(ra2.AX, wv2.y, c2_.y); \
        c3_.x = fmaf(ra3.AX, wv2.x, c3_.x); c3_.y = fmaf(ra3.AX, wv2.y, c3_.y); }
        PJSTEP(x, 0) PJSTEP(y, 1) PJSTEP(z, 2) PJSTEP(w, 3)
#undef PJSTEP
      }
      if (m == 0) {
#define QST(I, CI) { float2 r; r.x = CI.x * 0.25f; r.y = CI.y * 0.25f; \
        *(float2*)(qb + (size_t)(r0 + rb0 + I) * CC + c0) = r; }
        QST(0, c0_) QST(1, c1_) QST(2, c2_) QST(3, c3_)
#undef QST
      } else if (m == 1) {
#define KST(I, CI) *(float2*)(kb + (size_t)(r0 + rb0 + I) * CC + c0) = CI;
        KST(0, c0_) KST(1, c1_) KST(2, c2_) KST(3, c3_)
#undef KST
      } else if (m == 2) {
#define VST(I, CI) *(float2*)(vb + (size_t)(r0 + rb0 + I) * CC + c0) = CI;
        VST(0, c0_) VST(1, c1_) VST(2, c2_) VST(3, c3_)
#undef VST
      } else {
        float2 bgv = *(const float2*)(bg + c0);
#define GST(I, CI) { float2 r; r.x = sigm(CI.x + bgv.x); r.y = sigm(CI.y + bgv.y); \
        *(float2*)(gb + (size_t)(r0 + rb0 + I) * CC + c0) = r; }
        GST(0, c0_) GST(1, c1_) GST(2, c2_) GST(3, c3_)
#undef GST
      }
    }
  } else {
    __shared__ float wp[CPP * HH];
    __shared__ float gp[CPP];
    __shared__ float bp[CPP];
    if (tid < CPP * HH) wp[tid] = W_pair[tid];
    if (tid < CPP) { gp[tid] = gamma_p[tid]; bp[tid] = beta_p[tid]; }
    __syncthreads();

    const int i  = (b - 256) * 4 + (tid >> 7);
    const int w  = i >> 5;
    const int qq = i & 31;
    const int k  = tid & 127;
    const int j  = w * NQW + k - PADW;

    float bh[HH];
    if (j >= 0 && j < NTOK) {
      const float* p = pair + ((size_t)i * NTOK + j) * CPP;
      float x[CPP];
#pragma unroll
      for (int u4 = 0; u4 < CPP; u4 += 4) {
        float4 v = *(const float4*)(p + u4);
        x[u4] = v.x; x[u4 + 1] = v.y; x[u4 + 2] = v.z; x[u4 + 3] = v.w;
      }
      float s = 0.f;
#pragma unroll
      for (int c = 0; c < CPP; ++c) s += x[c];
      float mu = s * (1.0f / CPP);
      float vv = 0.f;
#pragma unroll
      for (int c = 0; c < CPP; ++c) { float d = x[c] - mu; vv = fmaf(d, d, vv); }
      float rs = rsqrtf(vv * (1.0f / CPP) + 1e-5f);
#pragma unroll
      for (int h = 0; h < HH; ++h) bh[h] = 0.f;
#pragma unroll
      for (int c = 0; c < CPP; ++c) {
        float y = (x[c] - mu) * rs * gp[c] + bp[c];
#pragma unroll
        for (int h = 0; h < HH; ++h) bh[h] = fmaf(y, wp[c * HH + h], bh[h]);
      }
    } else {
#pragma unroll
      for (int h = 0; h < HH; ++h) bh[h] = -10000.0f;
    }
#pragma unroll
    for (int h = 0; h < HH; ++h)
      bias[((size_t)((w * HH + h) * NQW + qq)) * NKW + k] = bh[h];
  }
}

// ---------------------------------------------------------------------------
// K2 fused attn + out-epilogue. 512 blocks x 256 threads.
// block = (w = b>>3, q4 = b&7): rows r0 = w*32 + q4*4 (4 rows, all 8 heads).
// Loop 4 head-pairs: stage K/V/bias for 2 heads; thread = (hp, qr, t in 0..31)
// owns (row qr, head 2it+hp, ks {t+32i}).  o -> LDS oacc[4][128].
// Then R8-proven 4-row epilogue in-place: u=(o*g)@Wo+bo; out=sigm(u@W_out+b2)*u.
// ---------------------------------------------------------------------------
__global__ __launch_bounds__(256) void attn_out_kernel(
    const float* __restrict__ qb, const float* __restrict__ kb,
    const float* __restrict__ vb, const float* __restrict__ gb,
    const float* __restrict__ bias,
    const float* __restrict__ Wo, const float* __restrict__ bo,
    const float* __restrict__ W_out, const float* __restrict__ b_out,
    float* __restrict__ out)
{
  __shared__ float qs[4][132];
  __shared__ float ks[2][NKW][20];
  __shared__ float vs[2][NKW][20];
  __shared__ float bs[2][4][132];
  __shared__ float oacc[4][132];
  __shared__ float og[4][132];
  __shared__ float us[4][132];

  const int b   = blockIdx.x;
  const int w   = b >> 3;
  const int q4  = b & 7;
  const int r0  = w * NQW + q4 * 4;      // global row base (4 rows)
  const int tid = threadIdx.x;

  // stage Q rows (full 128 dims) once
  {
    const int r = tid >> 6, c0 = (tid & 63) * 2;
    float2 qv = *(const float2*)(qb + (size_t)(r0 + r) * CC + c0);
    qs[r][c0]     = qv.x;
    qs[r][c0 + 1] = qv.y;
  }

#pragma unroll 1
  for (int it = 0; it < 4; ++it) {
    __syncthreads();   // previous iteration's reads done before restage

    // stage K/V for heads {2it, 2it+1}: 1024 float4 units, 4 per thread
#pragma unroll
    for (int s = 0; s < 4; ++s) {
      int u   = tid + s * 256;
      int hh  = u >> 9;
      int rem = u & 511;
      int kr  = rem >> 2, c4 = (rem & 3) * 4;
      int j   = w * NQW + kr - PADW;
      float4 kv = make_float4(0.f, 0.f, 0.f, 0.f);
      float4 vv = make_float4(0.f, 0.f, 0.f, 0.f);
      if (j >= 0 && j < NTOK) {
        kv = *(const float4*)(kb + (size_t)j * CC + (it * 2 + hh) * DHH + c4);
        vv = *(const float4*)(vb + (size_t)j * CC + (it * 2 + hh) * DHH + c4);
      }
      *(float4*)(&ks[hh][kr][c4]) = kv;
      *(float4*)(&vs[hh][kr][c4]) = vv;
    }
    // stage bias: 2 heads x 4 rows x 128 = 256 float4, 1 per thread
    {
      int hh  = tid >> 7;
      int rem = tid & 127;
      int qr  = rem >> 5, k4 = (rem & 31) * 4;
      float4 bv = *(const float4*)(bias +
          ((size_t)((w * HH + it * 2 + hh) * NQW + q4 * 4 + qr)) * NKW + k4);
      *(float4*)(&bs[hh][qr][k4]) = bv;
    }
    __syncthreads();

    const int hp = tid >> 7;           // 0..1
    const int t7 = tid & 127;
    const int qr = t7 >> 5;            // 0..3
    const int t  = t7 & 31;            // 0..31
    const int h  = it * 2 + hp;

    float4 q0 = *(float4*)(&qs[qr][h * DHH + 0]);
    float4 q1 = *(float4*)(&qs[qr][h * DHH + 4]);
    float4 q2 = *(float4*)(&qs[qr][h * DHH + 8]);
    float4 q3 = *(float4*)(&qs[qr][h * DHH + 12]);

    float l[4];
#pragma unroll
    for (int i = 0; i < 4; ++i) {
      int k = t + 32 * i;
      const float* kr_ = &ks[hp][k][0];
      float4 k0 = *(const float4*)(kr_);
      float4 k1 = *(const float4*)(kr_ + 4);
      float4 k2 = *(const float4*)(kr_ + 8);
      float4 k3 = *(const float4*)(kr_ + 12);
      float d = 0.f;
      d = fmaf(q0.x, k0.x, d); d = fmaf(q0.y, k0.y, d);
      d = fmaf(q0.z, k0.z, d); d = fmaf(q0.w, k0.w, d);
      d = fmaf(q1.x, k1.x, d); d = fmaf(q1.y, k1.y, d);
      d = fmaf(q1.z, k1.z, d); d = fmaf(q1.w, k1.w, d);
      d = fmaf(q2.x, k2.x, d); d = fmaf(q2.y, k2.y, d);
      d = fmaf(q2.z, k2.z, d); d = fmaf(q2.w, k2.w, d);
      d = fmaf(q3.x, k3.x, d); d = fmaf(q3.y, k3.y, d);
      d = fmaf(q3.z, k3.z, d); d = fmaf(q3.w, k3.w, d);
      l[i] = d + bs[hp][qr][k];
    }

    float m0 = fmaxf(fmaxf(l[0], l[1]), fmaxf(l[2], l[3]));
#pragma unroll
    for (int m = 1; m < 32; m <<= 1) m0 = fmaxf(m0, __shfl_xor(m0, m));
    float p[4];
    float s = 0.f;
#pragma unroll
    for (int i = 0; i < 4; ++i) { p[i] = expf(l[i] - m0); s += p[i]; }
#pragma unroll
    for (int m = 1; m < 32; m <<= 1) s += __shfl_xor(s, m);
    float inv = 1.0f / s;
#pragma unroll
    for (int i = 0; i < 4; ++i) p[i] *= inv;

    float o16[16];
#pragma unroll
    for (int d = 0; d < 16; ++d) o16[d] = 0.f;
#pragma unroll
    for (int i = 0; i < 4; ++i) {
      int k = t + 32 * i;
      const float* vr = &vs[hp][k][0];
      float4 v0 = *(const float4*)(vr);
      float4 v1 = *(const float4*)(vr + 4);
      float4 v2 = *(const float4*)(vr + 8);
      float4 v3 = *(const float4*)(vr + 12);
      float pa = p[i];
      o16[0]  = fmaf(pa, v0.x, o16[0]);  o16[1]  = fmaf(pa, v0.y, o16[1]);
      o16[2]  = fmaf(pa, v0.z, o16[2]);  o16[3]  = fmaf(pa, v0.w, o16[3]);
      o16[4]  = fmaf(pa, v1.x, o16[4]);  o16[5]  = fmaf(pa, v1.y, o16[5]);
      o16[6]  = fmaf(pa, v1.z, o16[6]);  o16[7]  = fmaf(pa, v1.w, o16[7]);
      o16[8]  = fmaf(pa, v2.x, o16[8]);  o16[9]  = fmaf(pa, v2.y, o16[9]);
      o16[10] = fmaf(pa, v2.z, o16[10]); o16[11] = fmaf(pa, v2.w, o16[11]);
      o16[12] = fmaf(pa, v3.x, o16[12]); o16[13] = fmaf(pa, v3.y, o16[13]);
      o16[14] = fmaf(pa, v3.z, o16[14]); o16[15] = fmaf(pa, v3.w, o16[15]);
    }
#pragma unroll
    for (int d = 0; d < 16; ++d) {
#pragma unroll
      for (int m = 1; m < 32; m <<= 1) o16[d] += __shfl_xor(o16[d], m);
    }
    float wsel = 0.f;
#pragma unroll
    for (int d = 0; d < 16; ++d) wsel = (t == d) ? o16[d] : wsel;
    if (t < 16) oacc[qr][h * DHH + t] = wsel;
  }
  __syncthreads();

  // ---- epilogue (R8 k3 body, 4 rows) ----
  {
    const int r = tid >> 6, c0 = (tid & 63) * 2;
    float2 g2 = *(const float2*)(gb + (size_t)(r0 + r) * CC + c0);
    og[r][c0]     = oacc[r][c0]     * g2.x;
    og[r][c0 + 1] = oacc[r][c0 + 1] * g2.y;
  }
  __syncthreads();

  const int rg = tid >> 7;
  const int cg = tid & 127;
  const int ra = rg * 2, rb = rg * 2 + 1;

  float u0 = 0.f, u1 = 0.f;
#pragma unroll 4
  for (int k4 = 0; k4 < 32; ++k4) {
    float4 a0 = *(const float4*)(&og[ra][k4 * 4]);
    float4 a1 = *(const float4*)(&og[rb][k4 * 4]);
#define O1STEP(AX, J) { \
    float wv = Wo[(k4 * 4 + J) * CC + cg]; \
    u0 = fmaf(a0.AX, wv, u0); u1 = fmaf(a1.AX, wv, u1); }
    O1STEP(x, 0) O1STEP(y, 1) O1STEP(z, 2) O1STEP(w, 3)
#undef O1STEP
  }
  float bov = bo[cg];
  u0 += bov; u1 += bov;
  us[ra][cg] = u0;
  us[rb][cg] = u1;
  __syncthreads();

  float a0s = 0.f, a1s = 0.f;
#pragma unroll 4
  for (int k4 = 0; k4 < 32; ++k4) {
    float4 a0 = *(const float4*)(&us[ra][k4 * 4]);
    float4 a1 = *(const float4*)(&us[rb][k4 * 4]);
#define O2STEP(AX, J) { \
    float wv = W_out[(k4 * 4 + J) * CC + cg]; \
    a0s = fmaf(a0.AX, wv, a0s); a1s = fmaf(a1.AX, wv, a1s); }
    O2STEP(x, 0) O2STEP(y, 1) O2STEP(z, 2) O2STEP(w, 3)
#undef O2STEP
  }
  float b2 = b_out[cg];
  out[(size_t)(r0 + ra) * CC + cg] = sigm(a0s + b2) * u0;
  out[(size_t)(r0 + rb) * CC + cg] = sigm(a1s + b2) * u1;
}

// ---------------------------------------------------------------------------
extern "C" void kernel_launch(void* const* d_in, const int* in_sizes, int n_in,
                              void* d_out, int out_size, void* d_ws, size_t ws_size,
                              hipStream_t stream) {
  (void)in_sizes; (void)n_in; (void)out_size; (void)ws_size;
  const float* x1      = (const float*)d_in[0];
  const float* x2      = (const float*)d_in[1];
  const float* pair    = (const float*)d_in[2];
  const float* gamma_s = (const float*)d_in[3];
  const float* Wg_ada  = (const float*)d_in[4];
  const float* bg_ada  = (const float*)d_in[5];
  const float* W_skip  = (const float*)d_in[6];
  const float* gamma_p = (const float*)d_in[7];
  const float* beta_p  = (const float*)d_in[8];
  const float* W_pair  = (const float*)d_in[9];
  const float* Wq      = (const float*)d_in[10];
  const float* Wk      = (const float*)d_in[11];
  const float* Wv      = (const float*)d_in[12];
  const float* Wg      = (const float*)d_in[13];
  const float* bg      = (const float*)d_in[14];
  const float* Wo      = (const float*)d_in[15];
  const float* bo      = (const float*)d_in[16];
  const float* W_out   = (const float*)d_in[17];
  const float* b_out   = (const float*)d_in[18];

  float* ws   = (float*)d_ws;
  const size_t NC = (size_t)NTOK * CC;   // 262144
  float* qb   = ws;
  float* kb   = ws + NC;
  float* vb   = ws + 2 * NC;
  float* gb   = ws + 3 * NC;
  float* bias = ws + 4 * NC;             // 2097152 floats

  k1_fused<<<768, 512, 0, stream>>>(x1, x2, gamma_s, Wg_ada, bg_ada, W_skip,
                                    Wq, Wk, Wv, Wg, bg,
                                    pair, gamma_p, beta_p, W_pair,
                                    qb, kb, vb, gb, bias);
  attn_out_kernel<<<512, 256, 0, stream>>>(qb, kb, vb, gb, bias,
                                           Wo, bo, W_out, b_out,
                                           (float*)d_out);
}

// Round 12
// 44.217 us; speedup vs baseline: 1.1366x; 1.1366x over previous
//
#include <hip/hip_runtime.h>
#include <math.h>

#define NTOK 2048
#define CC   128
#define CPP  16
#define HH   8
#define DHH  16
#define NQW  32
#define NKW  128
#define PADW 48
#define NBW  64

__device__ __forceinline__ float sigm(float x) { return 1.0f / (1.0f + expf(-x)); }

// ---------------------------------------------------------------------------
// K1: blocks [0,256): LN + adaLN GEMM + all 4 projections for 8 rows, in-LDS.
//     blocks [256,1280): bias (2 tokens each).   (R5/R8 proven — best anchor)
// ---------------------------------------------------------------------------
__global__ __launch_bounds__(256) void k1_fused(
    const float* __restrict__ x1, const float* __restrict__ x2,
    const float* __restrict__ gamma_s,
    const float* __restrict__ Wg_ada, const float* __restrict__ bg_ada,
    const float* __restrict__ W_skip,
    const float* __restrict__ Wq, const float* __restrict__ Wk,
    const float* __restrict__ Wv, const float* __restrict__ Wg,
    const float* __restrict__ bg,
    const float* __restrict__ pair,
    const float* __restrict__ gamma_p, const float* __restrict__ beta_p,
    const float* __restrict__ W_pair,
    float* __restrict__ qb, float* __restrict__ kb,
    float* __restrict__ vb, float* __restrict__ gb,
    float* __restrict__ bias)
{
  const int b   = blockIdx.x;
  const int tid = threadIdx.x;

  if (b < 256) {
    __shared__ float sln[8][132];
    __shared__ float aln[8][132];
    __shared__ float as_[8][132];
    const int r0 = b * 8;

    // ---- LN of 8 rows: 32 lanes per row, float4 per lane ----
    {
      const int r = tid >> 5, t = tid & 31, c0 = t * 4;
      const int row = r0 + r;
      float4 v1 = *(const float4*)(x1 + (size_t)row * CC + c0);
      float4 v2 = *(const float4*)(x2 + (size_t)row * CC + c0);
      float s1 = v1.x + v1.y + v1.z + v1.w;
      float p1 = v1.x * v1.x + v1.y * v1.y + v1.z * v1.z + v1.w * v1.w;
      float s2 = v2.x + v2.y + v2.z + v2.w;
      float p2 = v2.x * v2.x + v2.y * v2.y + v2.z * v2.z + v2.w * v2.w;
#pragma unroll
      for (int m = 1; m < 32; m <<= 1) {
        s1 += __shfl_xor(s1, m); p1 += __shfl_xor(p1, m);
        s2 += __shfl_xor(s2, m); p2 += __shfl_xor(p2, m);
      }
      const float rc = 1.0f / 128.0f;
      float mu1 = s1 * rc, mu2 = s2 * rc;
      float rs1 = rsqrtf(p1 * rc - mu1 * mu1 + 1e-5f);
      float rs2 = rsqrtf(p2 * rc - mu2 * mu2 + 1e-5f);
      float4 gs = *(const float4*)(gamma_s + c0);
      float4 al, sl;
      al.x = (v1.x - mu1) * rs1; al.y = (v1.y - mu1) * rs1;
      al.z = (v1.z - mu1) * rs1; al.w = (v1.w - mu1) * rs1;
      sl.x = (v2.x - mu2) * rs2 * gs.x; sl.y = (v2.y - mu2) * rs2 * gs.y;
      sl.z = (v2.z - mu2) * rs2 * gs.z; sl.w = (v2.w - mu2) * rs2 * gs.w;
      *(float4*)(&aln[r][c0]) = al;
      *(float4*)(&sln[r][c0]) = sl;
    }
    __syncthreads();

    // ---- stage-1 adaLN GEMM: thread (rh=tid>>7, cg=tid&127) -> 4 rows x 1 col
    {
      const int rh = tid >> 7, cg = tid & 127;
      float g0 = 0.f, g1 = 0.f, g2 = 0.f, g3 = 0.f;
      float s0 = 0.f, s1 = 0.f, s2 = 0.f, s3 = 0.f;
#pragma unroll 4
      for (int k4 = 0; k4 < 32; ++k4) {
        float4 a0 = *(const float4*)(&sln[rh * 4 + 0][k4 * 4]);
        float4 a1 = *(const float4*)(&sln[rh * 4 + 1][k4 * 4]);
        float4 a2 = *(const float4*)(&sln[rh * 4 + 2][k4 * 4]);
        float4 a3 = *(const float4*)(&sln[rh * 4 + 3][k4 * 4]);
#define S1STEP(AX, J) { \
        float wg = Wg_ada[(k4 * 4 + J) * CC + cg]; \
        float wk = W_skip[(k4 * 4 + J) * CC + cg]; \
        g0 = fmaf(a0.AX, wg, g0); g1 = fmaf(a1.AX, wg, g1); \
        g2 = fmaf(a2.AX, wg, g2); g3 = fmaf(a3.AX, wg, g3); \
        s0 = fmaf(a0.AX, wk, s0); s1 = fmaf(a1.AX, wk, s1); \
        s2 = fmaf(a2.AX, wk, s2); s3 = fmaf(a3.AX, wk, s3); }
        S1STEP(x, 0) S1STEP(y, 1) S1STEP(z, 2) S1STEP(w, 3)
#undef S1STEP
      }
      float bga = bg_ada[cg];
      as_[rh * 4 + 0][cg] = sigm(g0 + bga) * aln[rh * 4 + 0][cg] + s0;
      as_[rh * 4 + 1][cg] = sigm(g1 + bga) * aln[rh * 4 + 1][cg] + s1;
      as_[rh * 4 + 2][cg] = sigm(g2 + bga) * aln[rh * 4 + 2][cg] + s2;
      as_[rh * 4 + 3][cg] = sigm(g3 + bga) * aln[rh * 4 + 3][cg] + s3;
    }
    __syncthreads();

    // ---- projections: wave m = matrix, lane -> 2 cols, 8 rows ----
    {
      const int m  = tid >> 6;
      const int l  = tid & 63;
      const int c0 = l * 2;
      const float* Wm = (m == 0) ? Wq : (m == 1) ? Wk : (m == 2) ? Wv : Wg;
      float2 c0_ = {0.f, 0.f}, c1_ = {0.f, 0.f}, c2_ = {0.f, 0.f}, c3_ = {0.f, 0.f};
      float2 c4_ = {0.f, 0.f}, c5_ = {0.f, 0.f}, c6_ = {0.f, 0.f}, c7_ = {0.f, 0.f};
#pragma unroll 2
      for (int k4 = 0; k4 < 32; ++k4) {
        float4 ra0 = *(const float4*)(&as_[0][k4 * 4]);
        float4 ra1 = *(const float4*)(&as_[1][k4 * 4]);
        float4 ra2 = *(const float4*)(&as_[2][k4 * 4]);
        float4 ra3 = *(const float4*)(&as_[3][k4 * 4]);
        float4 ra4 = *(const float4*)(&as_[4][k4 * 4]);
        float4 ra5 = *(const float4*)(&as_[5][k4 * 4]);
        float4 ra6 = *(const float4*)(&as_[6][k4 * 4]);
        float4 ra7 = *(const float4*)(&as_[7][k4 * 4]);
#define PJSTEP(AX, J) { \
        float2 wv = *(const float2*)(Wm + (k4 * 4 + J) * CC + c0); \
        c0_.x = fmaf(ra0.AX, wv.x, c0_.x); c0_.y = fmaf(ra0.AX, wv.y, c0_.y); \
        c1_.x = fmaf(ra1.AX, wv.x, c1_.x); c1_.y = fmaf(ra1.AX, wv.y, c1_.y); \
        c2_.x = fmaf(ra2.AX, wv.x, c2_.x); c2_.y = fmaf(ra2.AX, wv.y, c2_.y); \
        c3_.x = fmaf(ra3.AX, wv.x, c3_.x); c3_.y = fmaf(ra3.AX, wv.y, c3_.y); \
        c4_.x = fmaf(ra4.AX, wv.x, c4_.x); c4_.y = fmaf(ra4.AX, wv.y, c4_.y); \
        c5_.x = fmaf(ra5.AX, wv.x, c5_.x); c5_.y = fmaf(ra5.AX, wv.y, c5_.y); \
        c6_.x = fmaf(ra6.AX, wv.x, c6_.x); c6_.y = fmaf(ra6.AX, wv.y, c6_.y); \
        c7_.x = fmaf(ra7.AX, wv.x, c7_.x); c7_.y = fmaf(ra7.AX, wv.y, c7_.y); }
        PJSTEP(x, 0) PJSTEP(y, 1) PJSTEP(z, 2) PJSTEP(w, 3)
#undef PJSTEP
      }
      if (m == 0) {
#define QST(I, CI) { float2 r; r.x = CI.x * 0.25f; r.y = CI.y * 0.25f; \
        *(float2*)(qb + (size_t)(r0 + I) * CC + c0) = r; }
        QST(0, c0_) QST(1, c1_) QST(2, c2_) QST(3, c3_)
        QST(4, c4_) QST(5, c5_) QST(6, c6_) QST(7, c7_)
#undef QST
      } else if (m == 1) {
#define KST(I, CI) *(float2*)(kb + (size_t)(r0 + I) * CC + c0) = CI;
        KST(0, c0_) KST(1, c1_) KST(2, c2_) KST(3, c3_)
        KST(4, c4_) KST(5, c5_) KST(6, c6_) KST(7, c7_)
#undef KST
      } else if (m == 2) {
#define VST(I, CI) *(float2*)(vb + (size_t)(r0 + I) * CC + c0) = CI;
        VST(0, c0_) VST(1, c1_) VST(2, c2_) VST(3, c3_)
        VST(4, c4_) VST(5, c5_) VST(6, c6_) VST(7, c7_)
#undef VST
      } else {
        float2 bgv = *(const float2*)(bg + c0);
#define GST(I, CI) { float2 r; r.x = sigm(CI.x + bgv.x); r.y = sigm(CI.y + bgv.y); \
        *(float2*)(gb + (size_t)(r0 + I) * CC + c0) = r; }
        GST(0, c0_) GST(1, c1_) GST(2, c2_) GST(3, c3_)
        GST(4, c4_) GST(5, c5_) GST(6, c6_) GST(7, c7_)
#undef GST
      }
    }
  } else {
    __shared__ float wp[CPP * HH];
    __shared__ float gp[CPP];
    __shared__ float bp[CPP];
    if (tid < CPP * HH) wp[tid] = W_pair[tid];
    if (tid < CPP) { gp[tid] = gamma_p[tid]; bp[tid] = beta_p[tid]; }
    __syncthreads();

    const int i  = (b - 256) * 2 + (tid >> 7);   // token 0..2047
    const int w  = i >> 5;
    const int qq = i & 31;
    const int k  = tid & 127;
    const int j  = w * NQW + k - PADW;

    float bh[HH];
    if (j >= 0 && j < NTOK) {
      const float* p = pair + ((size_t)i * NTOK + j) * CPP;
      float x[CPP];
#pragma unroll
      for (int u4 = 0; u4 < CPP; u4 += 4) {
        float4 v = *(const float4*)(p + u4);
        x[u4] = v.x; x[u4 + 1] = v.y; x[u4 + 2] = v.z; x[u4 + 3] = v.w;
      }
      float s = 0.f;
#pragma unroll
      for (int c = 0; c < CPP; ++c) s += x[c];
      float mu = s * (1.0f / CPP);
      float vv = 0.f;
#pragma unroll
      for (int c = 0; c < CPP; ++c) { float d = x[c] - mu; vv = fmaf(d, d, vv); }
      float rs = rsqrtf(vv * (1.0f / CPP) + 1e-5f);
#pragma unroll
      for (int h = 0; h < HH; ++h) bh[h] = 0.f;
#pragma unroll
      for (int c = 0; c < CPP; ++c) {
        float y = (x[c] - mu) * rs * gp[c] + bp[c];
#pragma unroll
        for (int h = 0; h < HH; ++h) bh[h] = fmaf(y, wp[c * HH + h], bh[h]);
      }
    } else {
#pragma unroll
      for (int h = 0; h < HH; ++h) bh[h] = -10000.0f;
    }
#pragma unroll
    for (int h = 0; h < HH; ++h)
      bias[((size_t)((w * HH + h) * NQW + qq)) * NKW + k] = bh[h];
  }
}

// ---------------------------------------------------------------------------
// K2: attention, 1024 blocks x 256 threads: block = (window, head, q-half).
// 16 q-rows per block; thread = (qr=tid>>4, t=tid&15) -> 1 q-row, 8 k-cols.
// (R5/R8 proven version)
// ---------------------------------------------------------------------------
__global__ __launch_bounds__(256) void attn_kernel(
    const float* __restrict__ qb, const float* __restrict__ kb,
    const float* __restrict__ vb, const float* __restrict__ bias,
    float* __restrict__ ob)
{
  __shared__ float qs[16][20];
  __shared__ float ks[NKW][20];
  __shared__ float vs[NKW][20];
  __shared__ float bs[16][132];
  const int u   = blockIdx.x;
  const int w   = u >> 4;
  const int h   = (u >> 1) & 7;
  const int qh  = u & 1;
  const int tid = threadIdx.x;

  if (tid < 64) {
    int qr = tid >> 2, c4 = (tid & 3) * 4;
    float4 v = *(const float4*)(qb + (size_t)(w * NQW + qh * 16 + qr) * CC + h * DHH + c4);
    *(float4*)(&qs[qr][c4]) = v;
  }
  {
    int kr = tid >> 1, c8 = (tid & 1) * 8;
    int j = w * NQW + kr - PADW;
    float4 k0 = make_float4(0.f, 0.f, 0.f, 0.f), k1 = k0, v0 = k0, v1 = k0;
    if (j >= 0 && j < NTOK) {
      const float* kp = kb + (size_t)j * CC + h * DHH + c8;
      const float* vp = vb + (size_t)j * CC + h * DHH + c8;
      k0 = *(const float4*)(kp);     k1 = *(const float4*)(kp + 4);
      v0 = *(const float4*)(vp);     v1 = *(const float4*)(vp + 4);
    }
    *(float4*)(&ks[kr][c8])     = k0;
    *(float4*)(&ks[kr][c8 + 4]) = k1;
    *(float4*)(&vs[kr][c8])     = v0;
    *(float4*)(&vs[kr][c8 + 4]) = v1;
  }
  {
    const float* bt = bias + (size_t)(w * HH + h) * NQW * NKW + (size_t)qh * 16 * NKW;
    int qr = tid >> 4, k8 = (tid & 15) * 8;
    float4 b0 = *(const float4*)(bt + qr * NKW + k8);
    float4 b1 = *(const float4*)(bt + qr * NKW + k8 + 4);
    *(float4*)(&bs[qr][k8])     = b0;
    *(float4*)(&bs[qr][k8 + 4]) = b1;
  }
  __syncthreads();

  const int qr = tid >> 4;   // 0..15
  const int t  = tid & 15;   // 0..15
  float4 q0 = *(float4*)(&qs[qr][0]);
  float4 q1 = *(float4*)(&qs[qr][4]);
  float4 q2 = *(float4*)(&qs[qr][8]);
  float4 q3 = *(float4*)(&qs[qr][12]);

  float l[8];
#pragma unroll
  for (int i = 0; i < 8; ++i) {
    int k = t + 16 * i;
    const float* kr_ = &ks[k][0];
    float4 k0 = *(const float4*)(kr_);
    float4 k1 = *(const float4*)(kr_ + 4);
    float4 k2 = *(const float4*)(kr_ + 8);
    float4 k3 = *(const float4*)(kr_ + 12);
    float d = 0.f;
    d = fmaf(q0.x, k0.x, d); d = fmaf(q0.y, k0.y, d);
    d = fmaf(q0.z, k0.z, d); d = fmaf(q0.w, k0.w, d);
    d = fmaf(q1.x, k1.x, d); d = fmaf(q1.y, k1.y, d);
    d = fmaf(q1.z, k1.z, d); d = fmaf(q1.w, k1.w, d);
    d = fmaf(q2.x, k2.x, d); d = fmaf(q2.y, k2.y, d);
    d = fmaf(q2.z, k2.z, d); d = fmaf(q2.w, k2.w, d);
    d = fmaf(q3.x, k3.x, d); d = fmaf(q3.y, k3.y, d);
    d = fmaf(q3.z, k3.z, d); d = fmaf(q3.w, k3.w, d);
    l[i] = d + bs[qr][k];
  }

  float m0 = l[0];
#pragma unroll
  for (int i = 1; i < 8; ++i) m0 = fmaxf(m0, l[i]);
  m0 = fmaxf(m0, __shfl_xor(m0, 1));
  m0 = fmaxf(m0, __shfl_xor(m0, 2));
  m0 = fmaxf(m0, __shfl_xor(m0, 4));
  m0 = fmaxf(m0, __shfl_xor(m0, 8));
  float s = 0.f;
  float p[8];
#pragma unroll
  for (int i = 0; i < 8; ++i) { p[i] = expf(l[i] - m0); s += p[i]; }
  s += __shfl_xor(s, 1);
  s += __shfl_xor(s, 2);
  s += __shfl_xor(s, 4);
  s += __shfl_xor(s, 8);
  float inv = 1.0f / s;
#pragma unroll
  for (int i = 0; i < 8; ++i) p[i] *= inv;

  float o[16];
#pragma unroll
  for (int d = 0; d < 16; ++d) o[d] = 0.f;
#pragma unroll
  for (int i = 0; i < 8; ++i) {
    int k = t + 16 * i;
    const float* vr = &vs[k][0];
    float4 v0 = *(const float4*)(vr);
    float4 v1 = *(const float4*)(vr + 4);
    float4 v2 = *(const float4*)(vr + 8);
    float4 v3 = *(const float4*)(vr + 12);
    float pa = p[i];
    o[0]  = fmaf(pa, v0.x, o[0]);  o[1]  = fmaf(pa, v0.y, o[1]);
    o[2]  = fmaf(pa, v0.z, o[2]);  o[3]  = fmaf(pa, v0.w, o[3]);
    o[4]  = fmaf(pa, v1.x, o[4]);  o[5]  = fmaf(pa, v1.y, o[5]);
    o[6]  = fmaf(pa, v1.z, o[6]);  o[7]  = fmaf(pa, v1.w, o[7]);
    o[8]  = fmaf(pa, v2.x, o[8]);  o[9]  = fmaf(pa, v2.y, o[9]);
    o[10] = fmaf(pa, v2.z, o[10]); o[11] = fmaf(pa, v2.w, o[11]);
    o[12] = fmaf(pa, v3.x, o[12]); o[13] = fmaf(pa, v3.y, o[13]);
    o[14] = fmaf(pa, v3.z, o[14]); o[15] = fmaf(pa, v3.w, o[15]);
  }
#pragma unroll
  for (int d = 0; d < 16; ++d) {
#pragma unroll
    for (int m = 1; m < 16; m <<= 1) o[d] += __shfl_xor(o[d], m);
  }
  float wsel = 0.f;
#pragma unroll
  for (int d = 0; d < 16; ++d) wsel = (t == d) ? o[d] : wsel;
  ob[(size_t)(w * NQW + qh * 16 + qr) * CC + h * DHH + t] = wsel;
}

// ---------------------------------------------------------------------------
// K3: u = (o*g)@Wo + bo ; out = sigmoid(u@W_out + b_out) * u
// 512 blocks x 256 threads, 4 rows/block.  (R8 proven version)
// ---------------------------------------------------------------------------
__global__ __launch_bounds__(256) void k3_out(
    const float* __restrict__ ob_, const float* __restrict__ gb_,
    const float* __restrict__ Wo, const float* __restrict__ bo,
    const float* __restrict__ W_out, const float* __restrict__ b_out,
    float* __restrict__ out)
{
  __shared__ float og[4][132];
  __shared__ float us[4][132];
  const int r0  = blockIdx.x * 4;
  const int tid = threadIdx.x;
  {
    const int r = tid >> 6, t = tid & 63, c0 = t * 2;
    float2 o2 = *(const float2*)(ob_ + (size_t)(r0 + r) * CC + c0);
    float2 g2 = *(const float2*)(gb_ + (size_t)(r0 + r) * CC + c0);
    og[r][c0]     = o2.x * g2.x;
    og[r][c0 + 1] = o2.y * g2.y;
  }
  __syncthreads();

  const int rg = tid >> 7;       // 0..1 -> rows {2rg, 2rg+1}
  const int cg = tid & 127;
  const int ra = rg * 2, rb = rg * 2 + 1;

  float u0 = 0.f, u1 = 0.f;
#pragma unroll 4
  for (int k4 = 0; k4 < 32; ++k4) {
    float4 a0 = *(const float4*)(&og[ra][k4 * 4]);
    float4 a1 = *(const float4*)(&og[rb][k4 * 4]);
#define O1STEP(AX, J) { \
    float wv = Wo[(k4 * 4 + J) * CC + cg]; \
    u0 = fmaf(a0.AX, wv, u0); u1 = fmaf(a1.AX, wv, u1); }
    O1STEP(x, 0) O1STEP(y, 1) O1STEP(z, 2) O1STEP(w, 3)
#undef O1STEP
  }
  float bov = bo[cg];
  u0 += bov; u1 += bov;
  us[ra][cg] = u0;
  us[rb][cg] = u1;
  __syncthreads();

  float a0s = 0.f, a1s = 0.f;
#pragma unroll 4
  for (int k4 = 0; k4 < 32; ++k4) {
    float4 a0 = *(const float4*)(&us[ra][k4 * 4]);
    float4 a1 = *(const float4*)(&us[rb][k4 * 4]);
#define O2STEP(AX, J) { \
    float wv = W_out[(k4 * 4 + J) * CC + cg]; \
    a0s = fmaf(a0.AX, wv, a0s); a1s = fmaf(a1.AX, wv, a1s); }
    O2STEP(x, 0) O2STEP(y, 1) O2STEP(z, 2) O2STEP(w, 3)
#undef O2STEP
  }
  float b2 = b_out[cg];
  out[(size_t)(r0 + ra) * CC + cg] = sigm(a0s + b2) * u0;
  out[(size_t)(r0 + rb) * CC + cg] = sigm(a1s + b2) * u1;
}

// ---------------------------------------------------------------------------
extern "C" void kernel_launch(void* const* d_in, const int* in_sizes, int n_in,
                              void* d_out, int out_size, void* d_ws, size_t ws_size,
                              hipStream_t stream) {
  (void)in_sizes; (void)n_in; (void)out_size; (void)ws_size;
  const float* x1      = (const float*)d_in[0];
  const float* x2      = (const float*)d_in[1];
  const float* pair    = (const float*)d_in[2];
  const float* gamma_s = (const float*)d_in[3];
  const float* Wg_ada  = (const float*)d_in[4];
  const float* bg_ada  = (const float*)d_in[5];
  const float* W_skip  = (const float*)d_in[6];
  const float* gamma_p = (const float*)d_in[7];
  const float* beta_p  = (const float*)d_in[8];
  const float* W_pair  = (const float*)d_in[9];
  const float* Wq      = (const float*)d_in[10];
  const float* Wk      = (const float*)d_in[11];
  const float* Wv      = (const float*)d_in[12];
  const float* Wg      = (const float*)d_in[13];
  const float* bg      = (const float*)d_in[14];
  const float* Wo      = (const float*)d_in[15];
  const float* bo      = (const float*)d_in[16];
  const float* W_out   = (const float*)d_in[17];
  const float* b_out   = (const float*)d_in[18];

  float* ws   = (float*)d_ws;
  const size_t NC = (size_t)NTOK * CC;   // 262144
  float* qb   = ws;
  float* kb   = ws + NC;
  float* vb   = ws + 2 * NC;
  float* gb   = ws + 3 * NC;
  float* obuf = ws + 4 * NC;
  float* bias = ws + 5 * NC;             // 64*8*32*128 = 2097152 floats

  k1_fused<<<1280, 256, 0, stream>>>(x1, x2, gamma_s, Wg_ada, bg_ada, W_skip,
                                     Wq, Wk, Wv, Wg, bg,
                                     pair, gamma_p, beta_p, W_pair,
                                     qb, kb, vb, gb, bias);
  attn_kernel<<<1024, 256, 0, stream>>>(qb, kb, vb, bias, obuf);
  k3_out<<<512, 256, 0, stream>>>(obuf, gb, Wo, bo, W_out, b_out,
                                  (float*)d_out);
}